// Round 2
// baseline (5159.671 us; speedup 1.0000x reference)
//
#include <hip/hip_runtime.h>

// BiLSTM + partial-CRF loss, MI355X (gfx950).
// R1: ws cut 407MB -> 84MiB (suspected OOB crash). Input projection fused
// into persistent LSTM (Wih+Whh both live in MFMA B-frags in registers);
// H stored bf16; x-part MFMAs overlap the producer-wait; bounded spin.
//
// Sizes: B=64, L=512, V=50000, E=256, H=512, T=32.
// Workspace (84 MiB):
//   x2  bf16 [512*64][256]    16777216 B  @ 0
//   H2  bf16 [512*64][1024]   67108864 B  @ 16777216   (hf|hb)
//   em  f32  [512*64][32]      4194304 B  @ 83886080
//   fwd f32 [64] @88080384, gold f32 [64] @88080640, cnt int[4096] @88080896

#define IMPOSSIBLE -10000.0f

typedef __attribute__((ext_vector_type(8))) short bf16x8;
typedef __attribute__((ext_vector_type(4))) float f32x4;
typedef unsigned int u32;
typedef unsigned short u16;

__device__ __forceinline__ u16 f2b(float f) {           // fp32 -> bf16 (RNE)
  union { float f; u32 u; } v; v.f = f;
  return (u16)((v.u + 0x7fffu + ((v.u >> 16) & 1u)) >> 16);
}
__device__ __forceinline__ float sigm(float x) { return 1.0f / (1.0f + __expf(-x)); }
__device__ __forceinline__ float tanh_f(float x) { return 1.0f - 2.0f / (__expf(2.0f * x) + 1.0f); }

// ---------------------------------------------------------------------------
__global__ void k_init(int* __restrict__ cnt) {
  const int i = blockIdx.x * 256 + threadIdx.x;
  if (i < 4096) cnt[i] = 0;
}

// ---------------------------------------------------------------------------
// x2[t*64+b][e] = bf16(emb[sents[b][t]][e]).  One block per t.
__global__ __launch_bounds__(256) void k_embed(
    const int* __restrict__ sents, const float* __restrict__ emb,
    u16* __restrict__ x2) {
  __shared__ int tok[64];
  const int tid = threadIdx.x, t = blockIdx.x;
  if (tid < 64) tok[tid] = sents[tid * 512 + t];
  __syncthreads();
#pragma unroll
  for (int i = 0; i < 16; ++i) {
    const int v = i * 256 + tid;          // float4 index
    const int row = v >> 6, ke = (v & 63) * 4;
    const float4 f = *(const float4*)(emb + (size_t)tok[row] * 256 + ke);
    ushort4 s; s.x = f2b(f.x); s.y = f2b(f.y); s.z = f2b(f.z); s.w = f2b(f.w);
    *(ushort4*)&x2[((size_t)t * 64 + row) * 256 + ke] = s;
  }
}

// ---------------------------------------------------------------------------
// Persistent BiLSTM, input projection fused. 256 wgs x 256 thr.
// wg -> (d=wid>>7, g=batch-group of 16, s=j-slice of 16); wave = gate.
// Registers per wave: Wih B-frags (K=256, 8 frags) + Whh B-frags (K=512, 16).
// Per step: x-MFMAs (h-independent, overlap wait) -> poll group counter
// (acquire) -> h A-frags direct from global bf16 H2 -> 16 MFMAs -> LDS gate
// exchange -> c/h update -> packed u32 agent store -> release counter add.
// 256 wgs on 256 CUs (4KB LDS) => all co-resident; spin is budget-bounded.
__global__ __launch_bounds__(256) void k_lstm(
    const float* __restrict__ Whf, const float* __restrict__ Whb,
    const float* __restrict__ Wif, const float* __restrict__ Wib,
    const float* __restrict__ bf_, const float* __restrict__ bb_,
    const u16* __restrict__ x2, u16* __restrict__ H2, int* __restrict__ cnt) {
  __shared__ float pre[4 * 16 * 16];
  const int tid = threadIdx.x, wid = blockIdx.x;
  const int d = wid >> 7, rr = wid & 127, g = rr >> 5, s = rr & 31;
  const int b0 = g * 16, j0 = s * 16;
  const float* __restrict__ Whh = d ? Whb : Whf;
  const float* __restrict__ Wih = d ? Wib : Wif;
  const float* __restrict__ bias = d ? bb_ : bf_;
  const int wv = tid >> 6, lane = tid & 63, lm = lane & 15, kh = lane >> 4;
  const int bl = tid >> 4, jj = tid & 15;

  bf16x8 wih_f[8], whh_f[16];   // B[k][n]: n=lane&15 (row gate*512+j0+n), k=kh*8+j+32*kt
  {
    const float* wp = Wih + (size_t)(wv * 512 + j0 + lm) * 256;
#pragma unroll
    for (int kt = 0; kt < 8; ++kt) {
      bf16x8 f;
#pragma unroll
      for (int j = 0; j < 8; ++j) f[j] = (short)f2b(wp[kt * 32 + kh * 8 + j]);
      wih_f[kt] = f;
    }
    const float* wq = Whh + (size_t)(wv * 512 + j0 + lm) * 512;
#pragma unroll
    for (int kt = 0; kt < 16; ++kt) {
      bf16x8 f;
#pragma unroll
      for (int j = 0; j < 8; ++j) f[j] = (short)f2b(wq[kt * 32 + kh * 8 + j]);
      whh_f[kt] = f;
    }
  }
  const float b_i = bias[0 * 512 + j0 + jj];
  const float b_f = bias[1 * 512 + j0 + jj];
  const float b_g = bias[2 * 512 + j0 + jj];
  const float b_o = bias[3 * 512 + j0 + jj];

  int* mycnt = cnt + (size_t)(d * 4 + g) * 512;
  float c = 0.f;
  int budget = 1 << 24;   // bounded spin: deadlock -> garbage result, not hang
  const f32x4 z = {0.f, 0.f, 0.f, 0.f};
#pragma unroll 1
  for (int it = 0; it < 512; ++it) {
    const int tt = d ? (511 - it) : it;
    // x-part (independent of h): overlaps the producer wait
    f32x4 acc = z;
    {
      const u16* xp = x2 + ((size_t)tt * 64 + b0 + lm) * 256 + kh * 8;
#pragma unroll
      for (int kt = 0; kt < 8; ++kt) {
        const bf16x8 a = *(const bf16x8*)(xp + kt * 32);
        acc = __builtin_amdgcn_mfma_f32_16x16x32_bf16(a, wih_f[kt], acc, 0, 0, 0);
      }
    }
    if (it > 0) {
      if (tid == 0) {
        while (__hip_atomic_load(&mycnt[it - 1], __ATOMIC_RELAXED, __HIP_MEMORY_SCOPE_AGENT) < 32 &&
               budget > 0) {
          __builtin_amdgcn_s_sleep(2); --budget;
        }
        (void)__hip_atomic_load(&mycnt[it - 1], __ATOMIC_ACQUIRE, __HIP_MEMORY_SCOPE_AGENT);
      }
      __syncthreads();
      const int tp = d ? (tt + 1) : (tt - 1);
      const u16* hp = H2 + ((size_t)tp * 64 + b0 + lm) * 1024 + d * 512 + kh * 8;
#pragma unroll
      for (int kt = 0; kt < 16; ++kt) {
        const bf16x8 a = *(const bf16x8*)(hp + kt * 32);
        acc = __builtin_amdgcn_mfma_f32_16x16x32_bf16(a, whh_f[kt], acc, 0, 0, 0);
      }
    }
    // C layout: col(=j)=lane&15, row(=batch)=kh*4+r
#pragma unroll
    for (int r = 0; r < 4; ++r) pre[wv * 256 + (kh * 4 + r) * 16 + lm] = acc[r];
    __syncthreads();
    const float pi = pre[0   + bl * 16 + jj] + b_i;
    const float pf = pre[256 + bl * 16 + jj] + b_f;
    const float pg = pre[512 + bl * 16 + jj] + b_g;
    const float po = pre[768 + bl * 16 + jj] + b_o;
    c = sigm(pf) * c + sigm(pi) * tanh_f(pg);
    const float h = sigm(po) * tanh_f(c);
    const float hpart = __shfl_xor(h, 1);
    if ((jj & 1) == 0) {    // pack (jj, jj+1) -> one u32, agent-visible store
      const u32 pk = (u32)f2b(h) | ((u32)f2b(hpart) << 16);
      const size_t idx = ((size_t)tt * 64 + b0 + bl) * 512 + (size_t)d * 256 + ((j0 + jj) >> 1);
      __hip_atomic_store((u32*)H2 + idx, pk, __ATOMIC_RELAXED, __HIP_MEMORY_SCOPE_AGENT);
    }
    __syncthreads();
    if (tid == 0)
      (void)__hip_atomic_fetch_add(&mycnt[it], 1, __ATOMIC_RELEASE, __HIP_MEMORY_SCOPE_AGENT);
  }
}

// ---------------------------------------------------------------------------
// em[t*64+b][tag] = [hf|hb] @ W_out^T + b_out.  One block per t (M=64,N=32,K=1024).
// W_out staged once in LDS (bf16, row-rotated by 8); A-frags direct from H2.
__global__ __launch_bounds__(256) void k_emproj(
    const u16* __restrict__ H2, const float* __restrict__ Wo,
    const float* __restrict__ bo, float* __restrict__ em) {
  __shared__ u16 Wl[32 * 1024];
  const int tid = threadIdx.x, mb = blockIdx.x;
  const int wv = tid >> 6, lane = tid & 63, lm = lane & 15, kh = lane >> 4;
#pragma unroll
  for (int i = 0; i < 32; ++i) {        // stage Wo 32x1024 f32 -> bf16, rotated
    const int row = i, k = tid * 4;
    const float4 f = *(const float4*)(Wo + (size_t)row * 1024 + k);
    ushort4 s; s.x = f2b(f.x); s.y = f2b(f.y); s.z = f2b(f.z); s.w = f2b(f.w);
    *(ushort4*)&Wl[row * 1024 + ((k + 8 * row) & 1023)] = s;
  }
  __syncthreads();
  const f32x4 z = {0.f, 0.f, 0.f, 0.f};
  f32x4 acc[2] = {z, z};
  const u16* ap = H2 + ((size_t)mb * 64 + wv * 16 + lm) * 1024 + kh * 8;
#pragma unroll 2
  for (int kt = 0; kt < 32; ++kt) {
    const bf16x8 a = *(const bf16x8*)(ap + kt * 32);
#pragma unroll
    for (int ni = 0; ni < 2; ++ni) {
      const int row = ni * 16 + lm;
      const bf16x8 b = *(const bf16x8*)&Wl[row * 1024 + ((kt * 32 + kh * 8 + 8 * row) & 1023)];
      acc[ni] = __builtin_amdgcn_mfma_f32_16x16x32_bf16(a, b, acc[ni], 0, 0, 0);
    }
  }
#pragma unroll
  for (int ni = 0; ni < 2; ++ni) {
    const int n = ni * 16 + lm;
    const float bv = bo[n];
#pragma unroll
    for (int r = 0; r < 4; ++r) {
      const int m = mb * 64 + wv * 16 + kh * 4 + r;
      em[(size_t)m * 32 + n] = acc[ni][r] + bv;
    }
  }
}

// ---------------------------------------------------------------------------
// CRF forward scans, fp32. One wave per (b, which); halves merged via shfl_xor(32).
__global__ __launch_bounds__(64) void k_crf(
    const float* __restrict__ em, const int* __restrict__ tgt,
    const float* __restrict__ trans, const float* __restrict__ stt,
    const float* __restrict__ ent, float* __restrict__ fwd, float* __restrict__ gold) {
  __shared__ float trl[1024];
  __shared__ float al[32];
  __shared__ int cur[32];
  const int lane = threadIdx.x;
  const int b = blockIdx.x >> 1;
  const int isnum = blockIdx.x & 1;
#pragma unroll
  for (int i = 0; i < 16; ++i) trl[i * 64 + lane] = trans[i * 64 + lane];
  const int k = lane & 31, j0 = (lane >> 5) * 16;
  {
    float a0 = stt[k] + em[(size_t)b * 32 + k];
    int p0 = 1;
    if (isnum) { p0 = tgt[((size_t)b * 512) * 32 + k]; if (p0 == 0) a0 = IMPOSSIBLE; }
    if (lane < 32) { al[k] = a0; cur[k] = p0; }
  }
  __syncthreads();
#pragma unroll 1
  for (int t = 1; t < 512; ++t) {
    const float emk = em[((size_t)t * 64 + b) * 32 + k];
    int nxt = 1;
    float e = emk;
    if (isnum) { nxt = tgt[((size_t)b * 512 + t) * 32 + k]; if (nxt == 0) e = IMPOSSIBLE; }
    float v[16];
    float m = -1e30f;
#pragma unroll
    for (int j = 0; j < 16; ++j) {
      float tr = trl[(j0 + j) * 32 + k];
      if (isnum && (cur[j0 + j] == 0 || nxt == 0)) tr = IMPOSSIBLE;
      v[j] = al[j0 + j] + tr;
      m = fmaxf(m, v[j]);
    }
    float ss = 0.f;
#pragma unroll
    for (int j = 0; j < 16; ++j) ss += __expf(v[j] - m);
    const float m2 = __shfl_xor(m, 32);
    const float s2 = __shfl_xor(ss, 32);
    const float M = fmaxf(m, m2);
    const float S = ss * __expf(m - M) + s2 * __expf(m2 - M);
    const float an = M + __logf(S) + e;
    __syncthreads();
    if (lane < 32) { al[k] = an; cur[k] = nxt; }
    __syncthreads();
  }
  float x;
  if (!isnum) {
    x = al[k] + ent[k];
  } else {
    const float et = ent[k] * (float)cur[k];
    x = al[k] + ((et == 0.f) ? IMPOSSIBLE : et);
  }
  float m = x;
#pragma unroll
  for (int o = 1; o < 32; o <<= 1) m = fmaxf(m, __shfl_xor(m, o));
  float ss = __expf(x - m);
#pragma unroll
  for (int o = 1; o < 32; o <<= 1) ss += __shfl_xor(ss, o);
  if (lane == 0) {
    const float r = m + __logf(ss);
    if (isnum) gold[b] = r; else fwd[b] = r;
  }
}

// ---------------------------------------------------------------------------
__global__ void k_red(const float* __restrict__ fwd, const float* __restrict__ gold,
                      float* __restrict__ out) {
  const int l = threadIdx.x;
  float v = fwd[l] - gold[l];
#pragma unroll
  for (int o = 1; o < 64; o <<= 1) v += __shfl_xor(v, o);
  if (l == 0) out[0] = v;
}

// ---------------------------------------------------------------------------
extern "C" void kernel_launch(void* const* d_in, const int* in_sizes, int n_in,
                              void* d_out, int out_size, void* d_ws, size_t ws_size,
                              hipStream_t stream) {
  (void)in_sizes; (void)n_in; (void)out_size; (void)ws_size;
  const int* sents = (const int*)d_in[0];
  const int* tgt = (const int*)d_in[2];
  const float* emb = (const float*)d_in[3];
  const float* Wif = (const float*)d_in[4];
  const float* Whf = (const float*)d_in[5];
  const float* bf_ = (const float*)d_in[6];
  const float* Wib = (const float*)d_in[7];
  const float* Whb = (const float*)d_in[8];
  const float* bb_ = (const float*)d_in[9];
  const float* Wo = (const float*)d_in[10];
  const float* bo = (const float*)d_in[11];
  const float* stt = (const float*)d_in[12];
  const float* ent = (const float*)d_in[13];
  const float* trans = (const float*)d_in[14];
  float* out = (float*)d_out;

  char* ws = (char*)d_ws;
  u16* x2 = (u16*)ws;                          // 16777216 B
  u16* H2 = (u16*)(ws + 16777216ull);          // 67108864 B
  float* em = (float*)(ws + 83886080ull);      //  4194304 B
  float* fwd = (float*)(ws + 88080384ull);     //      256 B
  float* gold = (float*)(ws + 88080640ull);    //      256 B
  int* cnt = (int*)(ws + 88080896ull);         //    16384 B

  k_init<<<dim3(16), dim3(256), 0, stream>>>(cnt);
  k_embed<<<dim3(512), dim3(256), 0, stream>>>(sents, emb, x2);
  k_lstm<<<dim3(256), dim3(256), 0, stream>>>(Whf, Whb, Wif, Wib, bf_, bb_, x2, H2, cnt);
  k_emproj<<<dim3(512), dim3(256), 0, stream>>>(H2, Wo, bo, em);
  k_crf<<<dim3(128), dim3(64), 0, stream>>>(em, tgt, trans, stt, ent, fwd, gold);
  k_red<<<dim3(1), dim3(64), 0, stream>>>(fwd, gold, out);
}

// Round 3
// 2961.166 us; speedup vs baseline: 1.7424x; 1.7424x over previous
//
#include <hip/hip_runtime.h>

// BiLSTM + partial-CRF loss, MI355X (gfx950).
// R2 post-mortem: 8.4us/step was agent-scope acquire/release (buffer_inv /
// buffer_wbl2 = cache-wide L2 ops) every step in every wg. R3: RELAXED-only
// protocol -- per-wg monotonic flags (no RMW fan-in), ordering via
// __syncthreads vmcnt drain + MALL-bypassing atomics; x-frag loads issued
// before the poll; k_crf prefetches t+1 and absorbs the final reduction.
//
// Sizes: B=64, L=512, V=50000, E=256, H=512, T=32.
// Workspace (~84 MiB):
//   x2  bf16 [512*64][256]    16777216 B @ 0
//   H2  bf16 [512*64][1024]   67108864 B @ 16777216   (hf|hb)
//   em  f32  [512*64][32]      4194304 B @ 83886080
//   flg int  [8 groups][32][16] 16384 B @ 88080384    (64B-spread flags)

#define IMPOSSIBLE -10000.0f

typedef __attribute__((ext_vector_type(8))) short bf16x8;
typedef __attribute__((ext_vector_type(4))) float f32x4;
typedef unsigned int u32;
typedef unsigned short u16;

__device__ __forceinline__ u16 f2b(float f) {           // fp32 -> bf16 (RNE)
  union { float f; u32 u; } v; v.f = f;
  return (u16)((v.u + 0x7fffu + ((v.u >> 16) & 1u)) >> 16);
}
__device__ __forceinline__ float sigm(float x) { return 1.0f / (1.0f + __expf(-x)); }
__device__ __forceinline__ float tanh_f(float x) { return 1.0f - 2.0f / (__expf(2.0f * x) + 1.0f); }

// ---------------------------------------------------------------------------
// Zero flags + out with MALL-bypassing stores (plain stores could sit dirty in
// one XCD's L2 while k_lstm's bypassing polls read stale MALL data).
__global__ void k_init(int* __restrict__ flg, float* __restrict__ out) {
  const int i = blockIdx.x * 256 + threadIdx.x;
  if (i < 4096)
    __hip_atomic_store(flg + i, 0, __ATOMIC_RELAXED, __HIP_MEMORY_SCOPE_AGENT);
  if (i == 4096)
    __hip_atomic_store((u32*)out, 0u, __ATOMIC_RELAXED, __HIP_MEMORY_SCOPE_AGENT);
}

// ---------------------------------------------------------------------------
// x2[t*64+b][e] = bf16(emb[sents[b][t]][e]).  One block per t.
__global__ __launch_bounds__(256) void k_embed(
    const int* __restrict__ sents, const float* __restrict__ emb,
    u16* __restrict__ x2) {
  __shared__ int tok[64];
  const int tid = threadIdx.x, t = blockIdx.x;
  if (tid < 64) tok[tid] = sents[tid * 512 + t];
  __syncthreads();
#pragma unroll
  for (int i = 0; i < 16; ++i) {
    const int v = i * 256 + tid;          // float4 index
    const int row = v >> 6, ke = (v & 63) * 4;
    const float4 f = *(const float4*)(emb + (size_t)tok[row] * 256 + ke);
    ushort4 s; s.x = f2b(f.x); s.y = f2b(f.y); s.z = f2b(f.z); s.w = f2b(f.w);
    *(ushort4*)&x2[((size_t)t * 64 + row) * 256 + ke] = s;
  }
}

// ---------------------------------------------------------------------------
// Persistent BiLSTM, input projection fused. 256 wgs x 256 thr, 1 wg/CU.
// wg -> (d, g=batch-group of 16, s=j-slice of 16); wave = gate. Wih+Whh live
// in MFMA B-frags in registers. RELAXED-only sync: after h stores drain
// (__syncthreads => vmcnt(0)), tid0 stores flag=it+1; consumers' lanes 0..31
// poll the group's 32 flags in parallel (bounded), then read h (lines are
// never cached before their flag, so plain b128 loads are safe and fresh).
__global__ __launch_bounds__(256, 1) void k_lstm(
    const float* __restrict__ Whf, const float* __restrict__ Whb,
    const float* __restrict__ Wif, const float* __restrict__ Wib,
    const float* __restrict__ bf_, const float* __restrict__ bb_,
    const u16* __restrict__ x2, u16* __restrict__ H2, int* __restrict__ flg) {
  __shared__ float pre[4 * 16 * 16];
  const int tid = threadIdx.x, wid = blockIdx.x;
  const int d = wid >> 7, rr = wid & 127, g = rr >> 5, s = rr & 31;
  const int b0 = g * 16, j0 = s * 16;
  const float* __restrict__ Whh = d ? Whb : Whf;
  const float* __restrict__ Wih = d ? Wib : Wif;
  const float* __restrict__ bias = d ? bb_ : bf_;
  const int wv = tid >> 6, lane = tid & 63, lm = lane & 15, kh = lane >> 4;
  const int bl = tid >> 4, jj = tid & 15;

  bf16x8 wih_f[8], whh_f[16];   // B[k][n]: n=lane&15 (row gate*512+j0+n), k=kh*8+j+32*kt
  {
    const float* wp = Wih + (size_t)(wv * 512 + j0 + lm) * 256;
#pragma unroll
    for (int kt = 0; kt < 8; ++kt) {
      bf16x8 f;
#pragma unroll
      for (int j = 0; j < 8; ++j) f[j] = (short)f2b(wp[kt * 32 + kh * 8 + j]);
      wih_f[kt] = f;
    }
    const float* wq = Whh + (size_t)(wv * 512 + j0 + lm) * 512;
#pragma unroll
    for (int kt = 0; kt < 16; ++kt) {
      bf16x8 f;
#pragma unroll
      for (int j = 0; j < 8; ++j) f[j] = (short)f2b(wq[kt * 32 + kh * 8 + j]);
      whh_f[kt] = f;
    }
  }
  const float b_i = bias[0 * 512 + j0 + jj];
  const float b_f = bias[1 * 512 + j0 + jj];
  const float b_g = bias[2 * 512 + j0 + jj];
  const float b_o = bias[3 * 512 + j0 + jj];

  int* gflg = flg + (size_t)(d * 4 + g) * 512;   // 32 flags, 16 ints (64B) apart
  float c = 0.f;
  const f32x4 z = {0.f, 0.f, 0.f, 0.f};
#pragma unroll 1
  for (int it = 0; it < 512; ++it) {
    const int tt = d ? (511 - it) : it;
    // x a-frags: issue loads now; they land while we poll.
    bf16x8 xa[8];
    {
      const u16* xp = x2 + ((size_t)tt * 64 + b0 + lm) * 256 + kh * 8;
#pragma unroll
      for (int kt = 0; kt < 8; ++kt) xa[kt] = *(const bf16x8*)(xp + kt * 32);
    }
    if (it > 0) {
      if (tid < 32) {
        const int* fp = gflg + tid * 16;
        int bud = 1 << 20;
        while (__hip_atomic_load(fp, __ATOMIC_RELAXED, __HIP_MEMORY_SCOPE_AGENT) < it &&
               --bud) {}
      }
      __syncthreads();
    }
    f32x4 acc = z;
#pragma unroll
    for (int kt = 0; kt < 8; ++kt)
      acc = __builtin_amdgcn_mfma_f32_16x16x32_bf16(xa[kt], wih_f[kt], acc, 0, 0, 0);
    if (it > 0) {
      const int tp = d ? (tt + 1) : (tt - 1);
      const u16* hp = H2 + ((size_t)tp * 64 + b0 + lm) * 1024 + d * 512 + kh * 8;
      bf16x8 ha[16];
#pragma unroll
      for (int kt = 0; kt < 16; ++kt) ha[kt] = *(const bf16x8*)(hp + kt * 32);
#pragma unroll
      for (int kt = 0; kt < 16; ++kt)
        acc = __builtin_amdgcn_mfma_f32_16x16x32_bf16(ha[kt], whh_f[kt], acc, 0, 0, 0);
    }
    // C layout: col(=j)=lane&15, row(=batch)=kh*4+r
#pragma unroll
    for (int r = 0; r < 4; ++r) pre[wv * 256 + (kh * 4 + r) * 16 + lm] = acc[r];
    __syncthreads();
    const float pi = pre[0   + bl * 16 + jj] + b_i;
    const float pf = pre[256 + bl * 16 + jj] + b_f;
    const float pg = pre[512 + bl * 16 + jj] + b_g;
    const float po = pre[768 + bl * 16 + jj] + b_o;
    c = sigm(pf) * c + sigm(pi) * tanh_f(pg);
    const float h = sigm(po) * tanh_f(c);
    const float hpart = __shfl_xor(h, 1);
    if ((jj & 1) == 0) {    // pack (jj, jj+1) -> one u32, MALL-bypassing store
      const u32 pk = (u32)f2b(h) | ((u32)f2b(hpart) << 16);
      const size_t idx = ((size_t)tt * 64 + b0 + bl) * 512 + (size_t)d * 256 + ((j0 + jj) >> 1);
      __hip_atomic_store((u32*)H2 + idx, pk, __ATOMIC_RELAXED, __HIP_MEMORY_SCOPE_AGENT);
    }
    __syncthreads();   // vmcnt(0): all waves' h stores acked at MALL
    if (tid == 0)
      __hip_atomic_store(gflg + s * 16, it + 1, __ATOMIC_RELAXED, __HIP_MEMORY_SCOPE_AGENT);
  }
}

// ---------------------------------------------------------------------------
// em[t*64+b][tag] = [hf|hb] @ W_out^T + b_out.  One block per t (M=64,N=32,K=1024).
__global__ __launch_bounds__(256) void k_emproj(
    const u16* __restrict__ H2, const float* __restrict__ Wo,
    const float* __restrict__ bo, float* __restrict__ em) {
  __shared__ u16 Wl[32 * 1024];
  const int tid = threadIdx.x, mb = blockIdx.x;
  const int wv = tid >> 6, lane = tid & 63, lm = lane & 15, kh = lane >> 4;
#pragma unroll
  for (int i = 0; i < 32; ++i) {        // stage Wo 32x1024 f32 -> bf16, rotated
    const int row = i, k = tid * 4;
    const float4 f = *(const float4*)(Wo + (size_t)row * 1024 + k);
    ushort4 s; s.x = f2b(f.x); s.y = f2b(f.y); s.z = f2b(f.z); s.w = f2b(f.w);
    *(ushort4*)&Wl[row * 1024 + ((k + 8 * row) & 1023)] = s;
  }
  __syncthreads();
  const f32x4 z = {0.f, 0.f, 0.f, 0.f};
  f32x4 acc[2] = {z, z};
  const u16* ap = H2 + ((size_t)mb * 64 + wv * 16 + lm) * 1024 + kh * 8;
#pragma unroll 2
  for (int kt = 0; kt < 32; ++kt) {
    const bf16x8 a = *(const bf16x8*)(ap + kt * 32);
#pragma unroll
    for (int ni = 0; ni < 2; ++ni) {
      const int row = ni * 16 + lm;
      const bf16x8 b = *(const bf16x8*)&Wl[row * 1024 + ((kt * 32 + kh * 8 + 8 * row) & 1023)];
      acc[ni] = __builtin_amdgcn_mfma_f32_16x16x32_bf16(a, b, acc[ni], 0, 0, 0);
    }
  }
#pragma unroll
  for (int ni = 0; ni < 2; ++ni) {
    const int n = ni * 16 + lm;
    const float bv = bo[n];
#pragma unroll
    for (int r = 0; r < 4; ++r) {
      const int m = mb * 64 + wv * 16 + kh * 4 + r;
      em[(size_t)m * 32 + n] = acc[ni][r] + bv;
    }
  }
}

// ---------------------------------------------------------------------------
// CRF forward scans, fp32. One wave per (b, which); halves merged via
// shfl_xor(32). Next step's em/tgt prefetched before the current logsumexp.
// Final reduction folded in via atomicAdd(out).
__global__ __launch_bounds__(64) void k_crf(
    const float* __restrict__ em, const int* __restrict__ tgt,
    const float* __restrict__ trans, const float* __restrict__ stt,
    const float* __restrict__ ent, float* __restrict__ out) {
  __shared__ float trl[1024];
  __shared__ float al[32];
  __shared__ int cur[32];
  const int lane = threadIdx.x;
  const int b = blockIdx.x >> 1;
  const int isnum = blockIdx.x & 1;
#pragma unroll
  for (int i = 0; i < 16; ++i) trl[i * 64 + lane] = trans[i * 64 + lane];
  const int k = lane & 31, j0 = (lane >> 5) * 16;
  {
    float a0 = stt[k] + em[(size_t)b * 32 + k];
    int p0 = 1;
    if (isnum) { p0 = tgt[((size_t)b * 512) * 32 + k]; if (p0 == 0) a0 = IMPOSSIBLE; }
    if (lane < 32) { al[k] = a0; cur[k] = p0; }
  }
  __syncthreads();
  float emk = em[((size_t)64 + b) * 32 + k];                    // t=1 prefetch
  int tg = isnum ? tgt[((size_t)b * 512 + 1) * 32 + k] : 1;
#pragma unroll 1
  for (int t = 1; t < 512; ++t) {
    const float e_raw = emk;
    const int nxt = tg;
    if (t + 1 < 512) {                                          // prefetch t+1
      emk = em[((size_t)(t + 1) * 64 + b) * 32 + k];
      if (isnum) tg = tgt[((size_t)b * 512 + t + 1) * 32 + k];
    }
    const float e = (isnum && nxt == 0) ? IMPOSSIBLE : e_raw;
    float v[16];
    float m = -1e30f;
#pragma unroll
    for (int j = 0; j < 16; ++j) {
      float tr = trl[(j0 + j) * 32 + k];
      if (isnum && (cur[j0 + j] == 0 || nxt == 0)) tr = IMPOSSIBLE;
      v[j] = al[j0 + j] + tr;
      m = fmaxf(m, v[j]);
    }
    float ss = 0.f;
#pragma unroll
    for (int j = 0; j < 16; ++j) ss += __expf(v[j] - m);
    const float m2 = __shfl_xor(m, 32);
    const float s2 = __shfl_xor(ss, 32);
    const float M = fmaxf(m, m2);
    const float S = ss * __expf(m - M) + s2 * __expf(m2 - M);
    const float an = M + __logf(S) + e;
    __syncthreads();
    if (lane < 32) { al[k] = an; cur[k] = nxt; }
    __syncthreads();
  }
  float x;
  if (!isnum) {
    x = al[k] + ent[k];
  } else {
    const float et = ent[k] * (float)cur[k];
    x = al[k] + ((et == 0.f) ? IMPOSSIBLE : et);
  }
  float m = x;
#pragma unroll
  for (int o = 1; o < 32; o <<= 1) m = fmaxf(m, __shfl_xor(m, o));
  float ss = __expf(x - m);
#pragma unroll
  for (int o = 1; o < 32; o <<= 1) ss += __shfl_xor(ss, o);
  if (lane == 0) {
    const float r = m + __logf(ss);
    atomicAdd(out, isnum ? -r : r);
  }
}

// ---------------------------------------------------------------------------
extern "C" void kernel_launch(void* const* d_in, const int* in_sizes, int n_in,
                              void* d_out, int out_size, void* d_ws, size_t ws_size,
                              hipStream_t stream) {
  (void)in_sizes; (void)n_in; (void)out_size; (void)ws_size;
  const int* sents = (const int*)d_in[0];
  const int* tgt = (const int*)d_in[2];
  const float* emb = (const float*)d_in[3];
  const float* Wif = (const float*)d_in[4];
  const float* Whf = (const float*)d_in[5];
  const float* bf_ = (const float*)d_in[6];
  const float* Wib = (const float*)d_in[7];
  const float* Whb = (const float*)d_in[8];
  const float* bb_ = (const float*)d_in[9];
  const float* Wo = (const float*)d_in[10];
  const float* bo = (const float*)d_in[11];
  const float* stt = (const float*)d_in[12];
  const float* ent = (const float*)d_in[13];
  const float* trans = (const float*)d_in[14];
  float* out = (float*)d_out;

  char* ws = (char*)d_ws;
  u16* x2 = (u16*)ws;                          // 16777216 B
  u16* H2 = (u16*)(ws + 16777216ull);          // 67108864 B
  float* em = (float*)(ws + 83886080ull);      //  4194304 B
  int* flg = (int*)(ws + 88080384ull);         //    16384 B

  k_init<<<dim3(17), dim3(256), 0, stream>>>(flg, out);
  k_embed<<<dim3(512), dim3(256), 0, stream>>>(sents, emb, x2);
  k_lstm<<<dim3(256), dim3(256), 0, stream>>>(Whf, Whb, Wif, Wib, bf_, bb_, x2, H2, flg);
  k_emproj<<<dim3(512), dim3(256), 0, stream>>>(H2, Wo, bo, em);
  k_crf<<<dim3(128), dim3(64), 0, stream>>>(em, tgt, trans, stt, ent, out);
}